// Round 4
// baseline (775.653 us; speedup 1.0000x reference)
//
#include <hip/hip_runtime.h>
#include <hip/hip_bf16.h>
#include <cstdint>
#include <cstddef>

// ---------------------------------------------------------------------------
// SwinLikeBlock, MI355X gfx950. Inputs f32, output f32.
// N=8, H=W=112, C=256, WS=7 -> 2048 windows x 49 tok, 8 heads x d=32,
// hidden=1024, T=100352.
//
// Round 10: mlp occupancy + traffic. Round-9 mlp: MfmaUtil 12.6 / VALUBusy 21
// / occ 38.9% / WRITE 216MB (2.1x ideal: 64B partial-line scalar RMW) /
// 12.8M bank conflicts (GELU u16 scatter, row stride 512B = 0 mod 32 banks).
//   mlp: 1024 thr (16 waves), nt=1, launch_bounds(1024,8) -> VGPR<=64,
//        LDS 66KB -> 2 blocks/CU = 32 waves/CU (100%). zb/hb rows padded
//        256->264 shorts (quad alias 4/8-way -> 2-way, free). Epilogue stages
//        acc2 in f32 LDS (stride 260) then float4-coalesced RMW (1KB/row).
//   attn: qkb rows padded 512->520 (same conflict fix), LN1 loads pipelined,
//        proj epilogue staged via dead yb (2x32-row batches) -> float4 RMW.
// LDS 16B-group XOR swizzle: group g of row r stored at (g&~7)|((g^r)&7).
// ---------------------------------------------------------------------------

typedef __bf16 bf16x8 __attribute__((ext_vector_type(8)));
typedef float f32x4 __attribute__((ext_vector_type(4)));

__device__ __forceinline__ unsigned short f2bf(float f){
    union{float f;uint32_t u;}c;c.f=f;uint32_t u=c.u;u+=0x7fffu+((u>>16)&1u);return (unsigned short)(u>>16);}
__device__ __forceinline__ float gelu_f(float x){ return 0.5f*x*(1.0f+erff(x*0.70710678118654752f)); }
__device__ __forceinline__ int swz(int row,int g){ return (g & ~7) | ((g ^ row) & 7); }

// f32 -> bf16 convert, n4 = count/4
__global__ __launch_bounds__(256) void conv_k(
    const float* __restrict__ src, unsigned short* __restrict__ dst, int n4)
{
    int i = blockIdx.x * 256 + threadIdx.x;
    if (i >= n4) return;
    float4 v = *(const float4*)(src + (size_t)i * 4);
    uint2 o;
    o.x = (uint32_t)f2bf(v.x) | ((uint32_t)f2bf(v.y) << 16);
    o.y = (uint32_t)f2bf(v.z) | ((uint32_t)f2bf(v.w) << 16);
    *(uint2*)(dst + (size_t)i * 4) = o;
}

// ---------------------------------------------------------------------------
// Kernel A: fused LN1 + qkv + window attention (MFMA) + proj + residual.
// One block (1024 thr, 16 waves) per window; waves (h, h+8) share head h.
// ---------------------------------------------------------------------------
#define QKP 520   // qkb row pitch in shorts (padded from 512)
__global__ __launch_bounds__(1024, 4) void attn_half_k(
    const float* __restrict__ x, const float* __restrict__ g1, const float* __restrict__ b1,
    const unsigned short* __restrict__ Wqkv, const float* __restrict__ bqkv,
    const unsigned short* __restrict__ Wproj, const float* __restrict__ bproj,
    float* __restrict__ out)
{
    __shared__ __align__(16) unsigned short yb[64 * 256];   // LN tile; later f32 stage (32 rows)
    __shared__ __align__(16) unsigned short qkb[64 * QKP];  // rows=tok, ch 0..255=Q(->P->attn out), 256..511=K
    __shared__ __align__(16) unsigned short vtb[256 * 64];  // rows=V channel, cols=tok
    const int t = threadIdx.x, lane = t & 63, w = t >> 6;   // w = 0..15
    const int quad = lane >> 4, l16 = lane & 15;
    const int widx = blockIdx.x;               // 0..2047
    const int img = widx >> 8, wi = widx & 255;
    const int wy = wi >> 4, wx = wi & 15;
    const size_t ibase = (size_t)img * 12544;

    // ---- LN1 into yb (swizzled); loads pipelined ahead of reductions ----
    {
        float4 xv[4];
        #pragma unroll
        for (int i = 0; i < 4; ++i) {
            int tok = w + i * 16;
            if (tok < 49) {
                int r = tok / 7, c = tok - r * 7;
                size_t gtok = ibase + (size_t)(wy * 7 + r) * 112 + (wx * 7 + c);
                xv[i] = *(const float4*)(x + gtok * 256 + lane * 4);
            }
        }
        float4 gv = *(const float4*)(g1 + lane * 4);
        float4 bv = *(const float4*)(b1 + lane * 4);
        #pragma unroll
        for (int i = 0; i < 4; ++i) {
            int tok = w + i * 16;
            if (tok < 49) {
                float4 v = xv[i];
                float s = v.x + v.y + v.z + v.w;
                float q = v.x*v.x + v.y*v.y + v.z*v.z + v.w*v.w;
                #pragma unroll
                for (int o = 32; o > 0; o >>= 1) { s += __shfl_xor(s, o); q += __shfl_xor(q, o); }
                float mean = s * (1.f/256.f), var = q * (1.f/256.f) - mean * mean;
                float inv = rsqrtf(var + 1e-5f);
                uint2 pk;
                pk.x = (uint32_t)f2bf((v.x-mean)*inv*gv.x+bv.x) | ((uint32_t)f2bf((v.y-mean)*inv*gv.y+bv.y) << 16);
                pk.y = (uint32_t)f2bf((v.z-mean)*inv*gv.z+bv.z) | ((uint32_t)f2bf((v.w-mean)*inv*gv.w+bv.w) << 16);
                *(uint2*)&yb[tok*256 + swz(tok, lane >> 1)*8 + (lane & 1)*4] = pk;
            }
        }
    }
    {   // zero pad rows 49..63 (keeps qkv pad rows finite: bias only)
        uint2 z2; z2.x = 0u; z2.y = 0u;
        for (int i = t; i < 960; i += 1024) {
            int row = 49 + (i >> 6), c4 = (i & 63) * 4;
            *(uint2*)&yb[row*256 + c4] = z2;
        }
    }
    __syncthreads();

    // ---- qkv GEMM: yb(64x256) @ Wqkv(768x256)^T + b -> qkb (Q|K) / vtb (V^T) ----
    {
        const int n0 = w * 48;
        f32x4 acc[4][3] = {};
        #pragma unroll
        for (int ks = 0; ks < 8; ++ks) {
            bf16x8 af[4], bfr[3];
            #pragma unroll
            for (int mt = 0; mt < 4; ++mt) {
                int m = mt * 16 + l16;
                af[mt] = *(const bf16x8*)&yb[m*256 + swz(m, ks*4 + quad)*8];
            }
            #pragma unroll
            for (int nt = 0; nt < 3; ++nt) {
                int n = n0 + nt * 16 + l16;
                bfr[nt] = *(const bf16x8*)(Wqkv + (size_t)n*256 + ks*32 + quad*8);
            }
            #pragma unroll
            for (int mt = 0; mt < 4; ++mt)
                #pragma unroll
                for (int nt = 0; nt < 3; ++nt)
                    acc[mt][nt] = __builtin_amdgcn_mfma_f32_16x16x32_bf16(
                        af[mt], bfr[nt], acc[mt][nt], 0, 0, 0);
        }
        #pragma unroll
        for (int mt = 0; mt < 4; ++mt)
            #pragma unroll
            for (int nt = 0; nt < 3; ++nt) {
                int col = n0 + nt * 16 + l16;
                float bb = bqkv[col];
                #pragma unroll
                for (int r = 0; r < 4; ++r) {
                    int row = mt * 16 + quad * 4 + r;
                    unsigned short val = f2bf(acc[mt][nt][r] + bb);
                    if (col < 512)
                        qkb[row*QKP + swz(row, col >> 3)*8 + (col & 7)] = val;
                    else
                        vtb[(col - 512)*64 + swz(col - 512, row >> 3)*8 + (row & 7)] = val;
                }
            }
    }
    __syncthreads();

    // ---- MFMA attention: waves (h, h+8) -> head h, 32 query rows each ----
    {
        const float scale = 0.17677669529663687f;   // 32^-0.5
        const int h = w & 7, half = w >> 3;
        unsigned short* pbuf = qkb + w * 1280;      // 32 rows x 40 shorts, per wave (2.5KB)

        // Load all S fragments from qkb into registers, then free qkb for P.
        bf16x8 aq[2], bk[4];
        #pragma unroll
        for (int mtl = 0; mtl < 2; ++mtl) {
            int m = half*32 + mtl*16 + l16;
            aq[mtl] = *(const bf16x8*)&qkb[m*QKP + swz(m, h*4 + quad)*8];
        }
        #pragma unroll
        for (int nt = 0; nt < 4; ++nt) {
            int n = nt * 16 + l16;
            bk[nt] = *(const bf16x8*)&qkb[n*QKP + swz(n, 32 + h*4 + quad)*8];
        }
        __syncthreads();   // all frag loads done before any wave writes P into qkb

        // S = Q @ K^T  (32x64 per wave, single K=32 step)
        f32x4 s[2][4] = {};
        #pragma unroll
        for (int mtl = 0; mtl < 2; ++mtl)
            #pragma unroll
            for (int nt = 0; nt < 4; ++nt)
                s[mtl][nt] = __builtin_amdgcn_mfma_f32_16x16x32_bf16(
                    aq[mtl], bk[nt], s[mtl][nt], 0, 0, 0);

        // softmax per row; cols 49..63 masked; normalize folded into P.
        uint32_t pk01[2][4], pk23[2][4];
        #pragma unroll
        for (int mtl = 0; mtl < 2; ++mtl)
            #pragma unroll
            for (int r = 0; r < 4; ++r) {
                float v0 = s[mtl][0][r];
                float v1 = s[mtl][1][r];
                float v2 = s[mtl][2][r];
                float v3 = (l16 == 0) ? s[mtl][3][r] : -1e30f;  // col 48+l16
                float mxv = fmaxf(fmaxf(v0, v1), fmaxf(v2, v3));
                #pragma unroll
                for (int off = 8; off > 0; off >>= 1) mxv = fmaxf(mxv, __shfl_xor(mxv, off));
                float p0 = __expf((v0 - mxv) * scale);
                float p1 = __expf((v1 - mxv) * scale);
                float p2 = __expf((v2 - mxv) * scale);
                float p3 = __expf((v3 - mxv) * scale);
                float ssum = p0 + p1 + p2 + p3;
                #pragma unroll
                for (int off = 8; off > 0; off >>= 1) ssum += __shfl_xor(ssum, off);
                float inv = 1.f / ssum;
                pk01[mtl][r] = (uint32_t)f2bf(p0*inv) | ((uint32_t)f2bf(p1*inv) << 16);
                pk23[mtl][r] = (uint32_t)f2bf(p2*inv) | ((uint32_t)f2bf(p3*inv) << 16);
            }

        // O = P @ V  (32x32 per wave, K=64), two K=32 rounds; P via pbuf
        // (row stride 40 shorts = 80B: 16B-aligned, 2-way bank alias max).
        f32x4 o[2][2] = {};
        #pragma unroll
        for (int kst = 0; kst < 2; ++kst) {
            #pragma unroll
            for (int mtl = 0; mtl < 2; ++mtl)
                #pragma unroll
                for (int r = 0; r < 4; ++r) {
                    int lr = mtl*16 + quad*4 + r;
                    uint32_t pw = kst ? pk23[mtl][r] : pk01[mtl][r];
                    pbuf[lr*40 + l16]      = (unsigned short)(pw & 0xffffu);
                    pbuf[lr*40 + 16 + l16] = (unsigned short)(pw >> 16);
                }
            bf16x8 ap[2], bv[2];
            #pragma unroll
            for (int mtl = 0; mtl < 2; ++mtl) {
                int m = mtl * 16 + l16;
                ap[mtl] = *(const bf16x8*)&pbuf[m*40 + quad*8];
            }
            #pragma unroll
            for (int nt = 0; nt < 2; ++nt) {
                int c = h*32 + nt*16 + l16;
                bv[nt] = *(const bf16x8*)&vtb[c*64 + swz(c, kst*4 + quad)*8];
            }
            #pragma unroll
            for (int mtl = 0; mtl < 2; ++mtl)
                #pragma unroll
                for (int nt = 0; nt < 2; ++nt)
                    o[mtl][nt] = __builtin_amdgcn_mfma_f32_16x16x32_bf16(
                        ap[mtl], bv[nt], o[mtl][nt], 0, 0, 0);
        }
        __syncthreads();   // all P reads done before O overwrites qkb

        // write O into Q region (zero pad rows so proj pad stays 0)
        #pragma unroll
        for (int mtl = 0; mtl < 2; ++mtl)
            #pragma unroll
            for (int nt = 0; nt < 2; ++nt)
                #pragma unroll
                for (int r = 0; r < 4; ++r) {
                    int row = half*32 + mtl*16 + quad*4 + r;
                    int ch = h*32 + nt*16 + l16;
                    float val = (row < 49) ? o[mtl][nt][r] : 0.f;
                    qkb[row*QKP + swz(row, ch >> 3)*8 + (ch & 7)] = f2bf(val);
                }
    }
    __syncthreads();

    // ---- proj: attnout(Q region of qkb) @ Wproj^T + b_proj + x -> out ----
    {
        const int n0 = w * 16;
        f32x4 acc[4];
        #pragma unroll
        for (int mt = 0; mt < 4; ++mt) acc[mt] = (f32x4){0.f,0.f,0.f,0.f};
        #pragma unroll
        for (int ks = 0; ks < 8; ++ks) {
            bf16x8 af[4], bfr;
            #pragma unroll
            for (int mt = 0; mt < 4; ++mt) {
                int m = mt * 16 + l16;
                af[mt] = *(const bf16x8*)&qkb[m*QKP + swz(m, ks*4 + quad)*8];
            }
            {
                int n = n0 + l16;
                bfr = *(const bf16x8*)(Wproj + (size_t)n*256 + ks*32 + quad*8);
            }
            #pragma unroll
            for (int mt = 0; mt < 4; ++mt)
                acc[mt] = __builtin_amdgcn_mfma_f32_16x16x32_bf16(
                    af[mt], bfr, acc[mt], 0, 0, 0);
        }
        // stage via yb (f32, 32 rows x 256) in two batches -> float4 RMW
        float* sb = (float*)yb;
        float4 bp = *(const float4*)(bproj + lane * 4);
        #pragma unroll
        for (int batch = 0; batch < 2; ++batch) {
            #pragma unroll
            for (int mt = 2*batch; mt < 2*batch + 2; ++mt)
                #pragma unroll
                for (int r = 0; r < 4; ++r) {
                    int row = mt * 16 + quad * 4 + r;
                    sb[(row - batch*32)*256 + n0 + l16] = acc[mt][r];
                }
            __syncthreads();
            #pragma unroll
            for (int i = 0; i < 2; ++i) {
                int row = batch*32 + w*2 + i;
                if (row < 49) {
                    int rr = row / 7, cc = row - rr * 7;
                    size_t gtok = ibase + (size_t)(wy * 7 + rr) * 112 + (wx * 7 + cc);
                    float4 xr = *(const float4*)(x + gtok * 256 + lane * 4);
                    float4 sv = *(const float4*)&sb[(row - batch*32)*256 + lane * 4];
                    float4 o4;
                    o4.x = sv.x + bp.x + xr.x;
                    o4.y = sv.y + bp.y + xr.y;
                    o4.z = sv.z + bp.z + xr.z;
                    o4.w = sv.w + bp.w + xr.w;
                    *(float4*)&out[gtok * 256 + lane * 4] = o4;
                }
            }
            __syncthreads();
        }
    }
}

// ---------------------------------------------------------------------------
// Kernel B: fused LN2 + fc1 + GELU + fc2 + residual, in-place f32 RMW on out.
// One block (1024 thr, 16 waves) per 64 tokens; wave w owns 16 output cols.
// LDS 2x64x264x2B = 66KB -> 2 blocks/CU; VGPR<=64 -> 32 waves/CU (100%).
// ---------------------------------------------------------------------------
#define MP 264    // zb/hb row pitch in shorts (padded from 256)
#define SP 260    // f32 stage row pitch
__global__ __launch_bounds__(1024, 8) void mlp_half_k(
    const float* __restrict__ g2, const float* __restrict__ b2,
    const unsigned short* __restrict__ W1, const float* __restrict__ bf1,
    const unsigned short* __restrict__ W2, const float* __restrict__ bf2,
    float* __restrict__ out)
{
    __shared__ __align__(16) unsigned short smem[2 * 64 * MP];
    unsigned short* zb = smem;
    unsigned short* hb = smem + 64 * MP;
    const int t = threadIdx.x, lane = t & 63, w = t >> 6;   // w = 0..15
    const int quad = lane >> 4, l16 = lane & 15;
    const size_t m0 = (size_t)blockIdx.x * 64;

    // ---- LN2 from f32 out into zb (4 pipelined rounds) ----
    {
        float4 xv[4];
        #pragma unroll
        for (int i = 0; i < 4; ++i) {
            size_t row = m0 + w + i * 16;
            xv[i] = *(const float4*)&out[row*256 + lane*4];
        }
        float4 gv = *(const float4*)(g2 + lane*4);
        float4 bv = *(const float4*)(b2 + lane*4);
        #pragma unroll
        for (int i = 0; i < 4; ++i) {
            int tok = w + i * 16;
            float4 v = xv[i];
            float s = v.x+v.y+v.z+v.w, q = v.x*v.x+v.y*v.y+v.z*v.z+v.w*v.w;
            #pragma unroll
            for (int o = 32; o > 0; o >>= 1) { s += __shfl_xor(s, o); q += __shfl_xor(q, o); }
            float mean = s*(1.f/256.f), var = q*(1.f/256.f) - mean*mean;
            float inv = rsqrtf(var + 1e-5f);
            uint2 pk;
            pk.x = (uint32_t)f2bf((v.x-mean)*inv*gv.x+bv.x) | ((uint32_t)f2bf((v.y-mean)*inv*gv.y+bv.y) << 16);
            pk.y = (uint32_t)f2bf((v.z-mean)*inv*gv.z+bv.z) | ((uint32_t)f2bf((v.w-mean)*inv*gv.w+bv.w) << 16);
            *(uint2*)&zb[tok*MP + swz(tok, lane >> 1)*8 + (lane & 1)*4] = pk;
        }
    }
    __syncthreads();

    f32x4 acc2[4] = {};
    for (int c = 0; c < 4; ++c) {                 // hidden chunks of 256
        const int hc0 = c * 256;
        f32x4 acc1[4] = {};
        #pragma unroll
        for (int ks = 0; ks < 8; ++ks) {          // fc1: K = 256
            bf16x8 af[4], bfr;
            #pragma unroll
            for (int mt = 0; mt < 4; ++mt) {
                int m = mt * 16 + l16;
                af[mt] = *(const bf16x8*)&zb[m*MP + swz(m, ks*4 + quad)*8];
            }
            {
                int n = hc0 + w * 16 + l16;
                bfr = *(const bf16x8*)(W1 + (size_t)n*256 + ks*32 + quad*8);
            }
            #pragma unroll
            for (int mt = 0; mt < 4; ++mt)
                acc1[mt] = __builtin_amdgcn_mfma_f32_16x16x32_bf16(
                    af[mt], bfr, acc1[mt], 0, 0, 0);
        }
        __syncthreads();                          // prev chunk's hb reads done
        {
            int lc = w * 16 + l16;
            float bb = bf1[hc0 + lc];
            #pragma unroll
            for (int mt = 0; mt < 4; ++mt)
                #pragma unroll
                for (int r = 0; r < 4; ++r) {
                    int row = mt * 16 + quad * 4 + r;
                    hb[row*MP + swz(row, lc >> 3)*8 + (lc & 7)] =
                        f2bf(gelu_f(acc1[mt][r] + bb));
                }
        }
        __syncthreads();
        #pragma unroll
        for (int ks = 0; ks < 8; ++ks) {          // fc2 partial-K
            bf16x8 af[4], bfr;
            #pragma unroll
            for (int mt = 0; mt < 4; ++mt) {
                int m = mt * 16 + l16;
                af[mt] = *(const bf16x8*)&hb[m*MP + swz(m, ks*4 + quad)*8];
            }
            {
                int n = w * 16 + l16;
                bfr = *(const bf16x8*)(W2 + (size_t)n*1024 + hc0 + ks*32 + quad*8);
            }
            #pragma unroll
            for (int mt = 0; mt < 4; ++mt)
                acc2[mt] = __builtin_amdgcn_mfma_f32_16x16x32_bf16(
                    af[mt], bfr, acc2[mt], 0, 0, 0);
        }
    }
    // ---- epilogue: + b_fc2, stage f32 in LDS, float4-coalesced residual RMW ----
    __syncthreads();                              // last fc2 hb/zb reads done
    {
        float* sbuf = (float*)smem;               // 64 x SP f32 (66KB buffer)
        int col = w * 16 + l16;
        float bb = bf2[col];
        #pragma unroll
        for (int mt = 0; mt < 4; ++mt)
            #pragma unroll
            for (int r = 0; r < 4; ++r) {
                int row = mt * 16 + quad * 4 + r;
                sbuf[row*SP + col] = acc2[mt][r] + bb;
            }
        __syncthreads();
        #pragma unroll
        for (int i = 0; i < 4; ++i) {
            int row = w * 4 + i;
            size_t g = (m0 + row) * 256 + lane * 4;
            float4 rv = *(const float4*)&out[g];
            float4 sv = *(const float4*)&sbuf[row*SP + lane*4];
            float4 o4;
            o4.x = rv.x + sv.x; o4.y = rv.y + sv.y;
            o4.z = rv.z + sv.z; o4.w = rv.w + sv.w;
            *(float4*)&out[g] = o4;
        }
    }
}

// ---------------------------------------------------------------------------
extern "C" void kernel_launch(void* const* d_in, const int* in_sizes, int n_in,
                              void* d_out, int out_size, void* d_ws, size_t ws_size,
                              hipStream_t stream)
{
    const float* x      = (const float*)d_in[0];
    // d_in[1]=H, d_in[2]=W : compile-time constants (112).
    const float* g1     = (const float*)d_in[3];
    const float* b1     = (const float*)d_in[4];
    const float* w_qkv  = (const float*)d_in[5];
    const float* b_qkv  = (const float*)d_in[6];
    const float* w_proj = (const float*)d_in[7];
    const float* b_proj = (const float*)d_in[8];
    const float* g2     = (const float*)d_in[9];
    const float* b2     = (const float*)d_in[10];
    const float* w_fc1  = (const float*)d_in[11];
    const float* b_fc1  = (const float*)d_in[12];
    const float* w_fc2  = (const float*)d_in[13];
    const float* b_fc2  = (const float*)d_in[14];
    float* out = (float*)d_out;                      // f32 output

    // ws: converted bf16 weights only — 786432 elems = 1.5 MiB
    unsigned short* cWqkv  = (unsigned short*)d_ws;  // 196608
    unsigned short* cWproj = cWqkv  + 196608;        // 65536
    unsigned short* cWfc1  = cWproj + 65536;         // 262144
    unsigned short* cWfc2  = cWfc1  + 262144;        // 262144

    conv_k<<<192, 256, 0, stream>>>(w_qkv,  cWqkv,  49152);
    conv_k<<<64,  256, 0, stream>>>(w_proj, cWproj, 16384);
    conv_k<<<256, 256, 0, stream>>>(w_fc1,  cWfc1,  65536);
    conv_k<<<256, 256, 0, stream>>>(w_fc2,  cWfc2,  65536);

    attn_half_k<<<2048, 1024, 0, stream>>>(x, g1, b1, cWqkv, b_qkv, cWproj, b_proj, out);
    mlp_half_k<<<1568, 1024, 0, stream>>>(g2, b2, cWfc1, b_fc1, cWfc2, b_fc2, out);
}

// Round 5
// 683.363 us; speedup vs baseline: 1.1351x; 1.1351x over previous
//
#include <hip/hip_runtime.h>
#include <hip/hip_bf16.h>
#include <cstdint>
#include <cstddef>

// ---------------------------------------------------------------------------
// SwinLikeBlock, MI355X gfx950. Inputs f32, output f32.
// N=8, H=W=112, C=256, WS=7 -> 2048 windows x 49 tok, 8 heads x d=32,
// hidden=1024, T=100352.
//
// Round 11: un-break the swizzle. Round-10 lesson: padding (MP=264/QKP=520)
// CANCELS the XOR group swizzle -> 93M conflict cycles + L2 thrash at 80% occ
// (hbm 404MB->1.03GB). Reverted to round-9 geometry (mlp 512 thr nt=2 MP=256,
// attn QKP=512), plus targeted fixes:
//   mlp fc1: paired output cols (2*l16, 2*l16+1) -> GELU stores are single
//        u32 per row (2-way banks, free) instead of 8-way u16 scatter.
//   mlp fc2: same pairing -> epilogue is float2 RMW, 128B contiguous per
//        quad-row = full 64B sectors (kills the 2.1x write amplification).
//   W1/W2 fragment register prefetch one ks ahead.
//   attn: QKP back to 512; keeps pipelined LN1 + staged float4 proj epilogue.
// LDS 16B-group XOR swizzle: group g of row r stored at (g&~7)|((g^r)&7).
// NEVER pad a swizzled buffer: bank = f(row_pitch) + XOR must not re-align.
// ---------------------------------------------------------------------------

typedef __bf16 bf16x8 __attribute__((ext_vector_type(8)));
typedef float f32x4 __attribute__((ext_vector_type(4)));

__device__ __forceinline__ unsigned short f2bf(float f){
    union{float f;uint32_t u;}c;c.f=f;uint32_t u=c.u;u+=0x7fffu+((u>>16)&1u);return (unsigned short)(u>>16);}
__device__ __forceinline__ float gelu_f(float x){ return 0.5f*x*(1.0f+erff(x*0.70710678118654752f)); }
__device__ __forceinline__ int swz(int row,int g){ return (g & ~7) | ((g ^ row) & 7); }

// f32 -> bf16 convert, n4 = count/4
__global__ __launch_bounds__(256) void conv_k(
    const float* __restrict__ src, unsigned short* __restrict__ dst, int n4)
{
    int i = blockIdx.x * 256 + threadIdx.x;
    if (i >= n4) return;
    float4 v = *(const float4*)(src + (size_t)i * 4);
    uint2 o;
    o.x = (uint32_t)f2bf(v.x) | ((uint32_t)f2bf(v.y) << 16);
    o.y = (uint32_t)f2bf(v.z) | ((uint32_t)f2bf(v.w) << 16);
    *(uint2*)(dst + (size_t)i * 4) = o;
}

// ---------------------------------------------------------------------------
// Kernel A: fused LN1 + qkv + window attention (MFMA) + proj + residual.
// One block (1024 thr, 16 waves) per window; waves (h, h+8) share head h.
// ---------------------------------------------------------------------------
__global__ __launch_bounds__(1024, 4) void attn_half_k(
    const float* __restrict__ x, const float* __restrict__ g1, const float* __restrict__ b1,
    const unsigned short* __restrict__ Wqkv, const float* __restrict__ bqkv,
    const unsigned short* __restrict__ Wproj, const float* __restrict__ bproj,
    float* __restrict__ out)
{
    __shared__ __align__(16) unsigned short yb[64 * 256];   // LN tile; later f32 stage (32 rows)
    __shared__ __align__(16) unsigned short qkb[64 * 512];  // rows=tok, ch 0..255=Q(->P->attn out), 256..511=K
    __shared__ __align__(16) unsigned short vtb[256 * 64];  // rows=V channel, cols=tok
    const int t = threadIdx.x, lane = t & 63, w = t >> 6;   // w = 0..15
    const int quad = lane >> 4, l16 = lane & 15;
    const int widx = blockIdx.x;               // 0..2047
    const int img = widx >> 8, wi = widx & 255;
    const int wy = wi >> 4, wx = wi & 15;
    const size_t ibase = (size_t)img * 12544;

    // ---- LN1 into yb (swizzled); loads pipelined ahead of reductions ----
    {
        float4 xv[4];
        #pragma unroll
        for (int i = 0; i < 4; ++i) {
            int tok = w + i * 16;
            if (tok < 49) {
                int r = tok / 7, c = tok - r * 7;
                size_t gtok = ibase + (size_t)(wy * 7 + r) * 112 + (wx * 7 + c);
                xv[i] = *(const float4*)(x + gtok * 256 + lane * 4);
            }
        }
        float4 gv = *(const float4*)(g1 + lane * 4);
        float4 bv = *(const float4*)(b1 + lane * 4);
        #pragma unroll
        for (int i = 0; i < 4; ++i) {
            int tok = w + i * 16;
            if (tok < 49) {
                float4 v = xv[i];
                float s = v.x + v.y + v.z + v.w;
                float q = v.x*v.x + v.y*v.y + v.z*v.z + v.w*v.w;
                #pragma unroll
                for (int o = 32; o > 0; o >>= 1) { s += __shfl_xor(s, o); q += __shfl_xor(q, o); }
                float mean = s * (1.f/256.f), var = q * (1.f/256.f) - mean * mean;
                float inv = rsqrtf(var + 1e-5f);
                uint2 pk;
                pk.x = (uint32_t)f2bf((v.x-mean)*inv*gv.x+bv.x) | ((uint32_t)f2bf((v.y-mean)*inv*gv.y+bv.y) << 16);
                pk.y = (uint32_t)f2bf((v.z-mean)*inv*gv.z+bv.z) | ((uint32_t)f2bf((v.w-mean)*inv*gv.w+bv.w) << 16);
                *(uint2*)&yb[tok*256 + swz(tok, lane >> 1)*8 + (lane & 1)*4] = pk;
            }
        }
    }
    {   // zero pad rows 49..63 (keeps qkv pad rows finite: bias only)
        uint2 z2; z2.x = 0u; z2.y = 0u;
        for (int i = t; i < 960; i += 1024) {
            int row = 49 + (i >> 6), c4 = (i & 63) * 4;
            *(uint2*)&yb[row*256 + c4] = z2;
        }
    }
    __syncthreads();

    // ---- qkv GEMM: yb(64x256) @ Wqkv(768x256)^T + b -> qkb (Q|K) / vtb (V^T) ----
    {
        const int n0 = w * 48;
        f32x4 acc[4][3] = {};
        #pragma unroll
        for (int ks = 0; ks < 8; ++ks) {
            bf16x8 af[4], bfr[3];
            #pragma unroll
            for (int mt = 0; mt < 4; ++mt) {
                int m = mt * 16 + l16;
                af[mt] = *(const bf16x8*)&yb[m*256 + swz(m, ks*4 + quad)*8];
            }
            #pragma unroll
            for (int nt = 0; nt < 3; ++nt) {
                int n = n0 + nt * 16 + l16;
                bfr[nt] = *(const bf16x8*)(Wqkv + (size_t)n*256 + ks*32 + quad*8);
            }
            #pragma unroll
            for (int mt = 0; mt < 4; ++mt)
                #pragma unroll
                for (int nt = 0; nt < 3; ++nt)
                    acc[mt][nt] = __builtin_amdgcn_mfma_f32_16x16x32_bf16(
                        af[mt], bfr[nt], acc[mt][nt], 0, 0, 0);
        }
        #pragma unroll
        for (int mt = 0; mt < 4; ++mt)
            #pragma unroll
            for (int nt = 0; nt < 3; ++nt) {
                int col = n0 + nt * 16 + l16;
                float bb = bqkv[col];
                #pragma unroll
                for (int r = 0; r < 4; ++r) {
                    int row = mt * 16 + quad * 4 + r;
                    unsigned short val = f2bf(acc[mt][nt][r] + bb);
                    if (col < 512)
                        qkb[row*512 + swz(row, col >> 3)*8 + (col & 7)] = val;
                    else
                        vtb[(col - 512)*64 + swz(col - 512, row >> 3)*8 + (row & 7)] = val;
                }
            }
    }
    __syncthreads();

    // ---- MFMA attention: waves (h, h+8) -> head h, 32 query rows each ----
    {
        const float scale = 0.17677669529663687f;   // 32^-0.5
        const int h = w & 7, half = w >> 3;
        unsigned short* pbuf = qkb + w * 1280;      // 32 rows x 40 shorts, per wave (2.5KB)

        // Load all S fragments from qkb into registers, then free qkb for P.
        bf16x8 aq[2], bk[4];
        #pragma unroll
        for (int mtl = 0; mtl < 2; ++mtl) {
            int m = half*32 + mtl*16 + l16;
            aq[mtl] = *(const bf16x8*)&qkb[m*512 + swz(m, h*4 + quad)*8];
        }
        #pragma unroll
        for (int nt = 0; nt < 4; ++nt) {
            int n = nt * 16 + l16;
            bk[nt] = *(const bf16x8*)&qkb[n*512 + swz(n, 32 + h*4 + quad)*8];
        }
        __syncthreads();   // all frag loads done before any wave writes P into qkb

        // S = Q @ K^T  (32x64 per wave, single K=32 step)
        f32x4 s[2][4] = {};
        #pragma unroll
        for (int mtl = 0; mtl < 2; ++mtl)
            #pragma unroll
            for (int nt = 0; nt < 4; ++nt)
                s[mtl][nt] = __builtin_amdgcn_mfma_f32_16x16x32_bf16(
                    aq[mtl], bk[nt], s[mtl][nt], 0, 0, 0);

        // softmax per row; cols 49..63 masked; normalize folded into P.
        uint32_t pk01[2][4], pk23[2][4];
        #pragma unroll
        for (int mtl = 0; mtl < 2; ++mtl)
            #pragma unroll
            for (int r = 0; r < 4; ++r) {
                float v0 = s[mtl][0][r];
                float v1 = s[mtl][1][r];
                float v2 = s[mtl][2][r];
                float v3 = (l16 == 0) ? s[mtl][3][r] : -1e30f;  // col 48+l16
                float mxv = fmaxf(fmaxf(v0, v1), fmaxf(v2, v3));
                #pragma unroll
                for (int off = 8; off > 0; off >>= 1) mxv = fmaxf(mxv, __shfl_xor(mxv, off));
                float p0 = __expf((v0 - mxv) * scale);
                float p1 = __expf((v1 - mxv) * scale);
                float p2 = __expf((v2 - mxv) * scale);
                float p3 = __expf((v3 - mxv) * scale);
                float ssum = p0 + p1 + p2 + p3;
                #pragma unroll
                for (int off = 8; off > 0; off >>= 1) ssum += __shfl_xor(ssum, off);
                float inv = 1.f / ssum;
                pk01[mtl][r] = (uint32_t)f2bf(p0*inv) | ((uint32_t)f2bf(p1*inv) << 16);
                pk23[mtl][r] = (uint32_t)f2bf(p2*inv) | ((uint32_t)f2bf(p3*inv) << 16);
            }

        // O = P @ V  (32x32 per wave, K=64), two K=32 rounds; P via pbuf
        // (row stride 40 shorts = 80B: 16B-aligned, 2-way bank alias max).
        f32x4 o[2][2] = {};
        #pragma unroll
        for (int kst = 0; kst < 2; ++kst) {
            #pragma unroll
            for (int mtl = 0; mtl < 2; ++mtl)
                #pragma unroll
                for (int r = 0; r < 4; ++r) {
                    int lr = mtl*16 + quad*4 + r;
                    uint32_t pw = kst ? pk23[mtl][r] : pk01[mtl][r];
                    pbuf[lr*40 + l16]      = (unsigned short)(pw & 0xffffu);
                    pbuf[lr*40 + 16 + l16] = (unsigned short)(pw >> 16);
                }
            bf16x8 ap[2], bv[2];
            #pragma unroll
            for (int mtl = 0; mtl < 2; ++mtl) {
                int m = mtl * 16 + l16;
                ap[mtl] = *(const bf16x8*)&pbuf[m*40 + quad*8];
            }
            #pragma unroll
            for (int nt = 0; nt < 2; ++nt) {
                int c = h*32 + nt*16 + l16;
                bv[nt] = *(const bf16x8*)&vtb[c*64 + swz(c, kst*4 + quad)*8];
            }
            #pragma unroll
            for (int mtl = 0; mtl < 2; ++mtl)
                #pragma unroll
                for (int nt = 0; nt < 2; ++nt)
                    o[mtl][nt] = __builtin_amdgcn_mfma_f32_16x16x32_bf16(
                        ap[mtl], bv[nt], o[mtl][nt], 0, 0, 0);
        }
        __syncthreads();   // all P reads done before O overwrites qkb

        // write O into Q region (zero pad rows so proj pad stays 0)
        #pragma unroll
        for (int mtl = 0; mtl < 2; ++mtl)
            #pragma unroll
            for (int nt = 0; nt < 2; ++nt)
                #pragma unroll
                for (int r = 0; r < 4; ++r) {
                    int row = half*32 + mtl*16 + quad*4 + r;
                    int ch = h*32 + nt*16 + l16;
                    float val = (row < 49) ? o[mtl][nt][r] : 0.f;
                    qkb[row*512 + swz(row, ch >> 3)*8 + (ch & 7)] = f2bf(val);
                }
    }
    __syncthreads();

    // ---- proj: attnout(Q region of qkb) @ Wproj^T + b_proj + x -> out ----
    {
        const int n0 = w * 16;
        f32x4 acc[4];
        #pragma unroll
        for (int mt = 0; mt < 4; ++mt) acc[mt] = (f32x4){0.f,0.f,0.f,0.f};
        #pragma unroll
        for (int ks = 0; ks < 8; ++ks) {
            bf16x8 af[4], bfr;
            #pragma unroll
            for (int mt = 0; mt < 4; ++mt) {
                int m = mt * 16 + l16;
                af[mt] = *(const bf16x8*)&qkb[m*512 + swz(m, ks*4 + quad)*8];
            }
            {
                int n = n0 + l16;
                bfr = *(const bf16x8*)(Wproj + (size_t)n*256 + ks*32 + quad*8);
            }
            #pragma unroll
            for (int mt = 0; mt < 4; ++mt)
                acc[mt] = __builtin_amdgcn_mfma_f32_16x16x32_bf16(
                    af[mt], bfr, acc[mt], 0, 0, 0);
        }
        // stage via yb (f32, 32 rows x 256) in two batches -> float4 RMW
        float* sb = (float*)yb;
        float4 bp = *(const float4*)(bproj + lane * 4);
        #pragma unroll
        for (int batch = 0; batch < 2; ++batch) {
            #pragma unroll
            for (int mt = 2*batch; mt < 2*batch + 2; ++mt)
                #pragma unroll
                for (int r = 0; r < 4; ++r) {
                    int row = mt * 16 + quad * 4 + r;
                    sb[(row - batch*32)*256 + n0 + l16] = acc[mt][r];
                }
            __syncthreads();
            #pragma unroll
            for (int i = 0; i < 2; ++i) {
                int row = batch*32 + w*2 + i;
                if (row < 49) {
                    int rr = row / 7, cc = row - rr * 7;
                    size_t gtok = ibase + (size_t)(wy * 7 + rr) * 112 + (wx * 7 + cc);
                    float4 xr = *(const float4*)(x + gtok * 256 + lane * 4);
                    float4 sv = *(const float4*)&sb[(row - batch*32)*256 + lane * 4];
                    float4 o4;
                    o4.x = sv.x + bp.x + xr.x;
                    o4.y = sv.y + bp.y + xr.y;
                    o4.z = sv.z + bp.z + xr.z;
                    o4.w = sv.w + bp.w + xr.w;
                    *(float4*)&out[gtok * 256 + lane * 4] = o4;
                }
            }
            __syncthreads();
        }
    }
}

// ---------------------------------------------------------------------------
// Kernel B: fused LN2 + fc1 + GELU + fc2 + residual, in-place f32 RMW on out.
// One block (512 thr, 8 waves) per 64 tokens; wave w owns 32 output cols,
// PAIRED per lane: cols (w*32 + 2*l16, w*32 + 2*l16 + 1).
// LDS zb + hb = 64 KB -> 2 blocks/CU; pure XOR swizzle (MP=256, no padding).
// ---------------------------------------------------------------------------
__global__ __launch_bounds__(512, 4) void mlp_half_k(
    const float* __restrict__ g2, const float* __restrict__ b2,
    const unsigned short* __restrict__ W1, const float* __restrict__ bf1,
    const unsigned short* __restrict__ W2, const float* __restrict__ bf2,
    float* __restrict__ out)
{
    __shared__ __align__(16) unsigned short zb[64 * 256];
    __shared__ __align__(16) unsigned short hb[64 * 256];
    const int t = threadIdx.x, lane = t & 63, w = t >> 6;   // w = 0..7
    const int quad = lane >> 4, l16 = lane & 15;
    const size_t m0 = (size_t)blockIdx.x * 64;
    const int cpair = w * 32 + 2 * l16;        // this lane's paired col base

    // ---- LN2 from f32 out into zb ----
    for (int tok = w; tok < 64; tok += 8) {
        size_t row = m0 + tok;
        float4 v = *(const float4*)&out[row*256 + lane*4];
        float s = v.x+v.y+v.z+v.w, q = v.x*v.x+v.y*v.y+v.z*v.z+v.w*v.w;
        #pragma unroll
        for (int o = 32; o > 0; o >>= 1) { s += __shfl_xor(s, o); q += __shfl_xor(q, o); }
        float mean = s*(1.f/256.f), var = q*(1.f/256.f) - mean*mean;
        float inv = rsqrtf(var + 1e-5f);
        float4 gv = *(const float4*)(g2 + lane*4);
        float4 bv = *(const float4*)(b2 + lane*4);
        uint2 pk;
        pk.x = (uint32_t)f2bf((v.x-mean)*inv*gv.x+bv.x) | ((uint32_t)f2bf((v.y-mean)*inv*gv.y+bv.y) << 16);
        pk.y = (uint32_t)f2bf((v.z-mean)*inv*gv.z+bv.z) | ((uint32_t)f2bf((v.w-mean)*inv*gv.w+bv.w) << 16);
        *(uint2*)&zb[tok*256 + swz(tok, lane >> 1)*8 + (lane & 1)*4] = pk;
    }
    __syncthreads();

    f32x4 acc2[4][2] = {};
    for (int c = 0; c < 4; ++c) {                 // hidden chunks of 256
        const int hc0 = c * 256;
        f32x4 acc1[4][2] = {};
        // fc1: K = 256, B cols paired (2*l16, 2*l16+1); prefetch one ks ahead
        bf16x8 bnx[2];
        #pragma unroll
        for (int nt = 0; nt < 2; ++nt) {
            int n = hc0 + cpair + nt;
            bnx[nt] = *(const bf16x8*)(W1 + (size_t)n*256 + quad*8);
        }
        #pragma unroll
        for (int ks = 0; ks < 8; ++ks) {
            bf16x8 af[4], bcur[2];
            bcur[0] = bnx[0]; bcur[1] = bnx[1];
            if (ks < 7) {
                #pragma unroll
                for (int nt = 0; nt < 2; ++nt) {
                    int n = hc0 + cpair + nt;
                    bnx[nt] = *(const bf16x8*)(W1 + (size_t)n*256 + (ks+1)*32 + quad*8);
                }
            }
            #pragma unroll
            for (int mt = 0; mt < 4; ++mt) {
                int m = mt * 16 + l16;
                af[mt] = *(const bf16x8*)&zb[m*256 + swz(m, ks*4 + quad)*8];
            }
            #pragma unroll
            for (int mt = 0; mt < 4; ++mt)
                #pragma unroll
                for (int nt = 0; nt < 2; ++nt)
                    acc1[mt][nt] = __builtin_amdgcn_mfma_f32_16x16x32_bf16(
                        af[mt], bcur[nt], acc1[mt][nt], 0, 0, 0);
        }
        __syncthreads();                          // prev chunk's hb reads done
        {   // GELU + bias -> hb as single u32 per row (paired adjacent cols)
            float bb0 = bf1[hc0 + cpair];
            float bb1 = bf1[hc0 + cpair + 1];
            #pragma unroll
            for (int mt = 0; mt < 4; ++mt)
                #pragma unroll
                for (int r = 0; r < 4; ++r) {
                    int row = mt * 16 + quad * 4 + r;
                    uint32_t pk = (uint32_t)f2bf(gelu_f(acc1[mt][0][r] + bb0))
                                | ((uint32_t)f2bf(gelu_f(acc1[mt][1][r] + bb1)) << 16);
                    *(uint32_t*)&hb[row*256 + swz(row, cpair >> 3)*8 + (cpair & 7)] = pk;
                }
        }
        __syncthreads();
        // fc2 partial-K, B cols paired; prefetch one ks ahead
        bf16x8 b2x[2];
        #pragma unroll
        for (int nt = 0; nt < 2; ++nt) {
            int n = cpair + nt;
            b2x[nt] = *(const bf16x8*)(W2 + (size_t)n*1024 + hc0 + quad*8);
        }
        #pragma unroll
        for (int ks = 0; ks < 8; ++ks) {
            bf16x8 af[4], bcur[2];
            bcur[0] = b2x[0]; bcur[1] = b2x[1];
            if (ks < 7) {
                #pragma unroll
                for (int nt = 0; nt < 2; ++nt) {
                    int n = cpair + nt;
                    b2x[nt] = *(const bf16x8*)(W2 + (size_t)n*1024 + hc0 + (ks+1)*32 + quad*8);
                }
            }
            #pragma unroll
            for (int mt = 0; mt < 4; ++mt) {
                int m = mt * 16 + l16;
                af[mt] = *(const bf16x8*)&hb[m*256 + swz(m, ks*4 + quad)*8];
            }
            #pragma unroll
            for (int mt = 0; mt < 4; ++mt)
                #pragma unroll
                for (int nt = 0; nt < 2; ++nt)
                    acc2[mt][nt] = __builtin_amdgcn_mfma_f32_16x16x32_bf16(
                        af[mt], bcur[nt], acc2[mt][nt], 0, 0, 0);
        }
    }
    // ---- epilogue: + b_fc2 + residual, float2 RMW (full 64B sectors) ----
    {
        float bb0 = bf2[cpair];
        float bb1 = bf2[cpair + 1];
        #pragma unroll
        for (int mt = 0; mt < 4; ++mt)
            #pragma unroll
            for (int r = 0; r < 4; ++r) {
                size_t row = m0 + mt * 16 + quad * 4 + r;
                float2 rv = *(const float2*)&out[row*256 + cpair];
                float2 o2;
                o2.x = acc2[mt][0][r] + bb0 + rv.x;
                o2.y = acc2[mt][1][r] + bb1 + rv.y;
                *(float2*)&out[row*256 + cpair] = o2;
            }
    }
}

// ---------------------------------------------------------------------------
extern "C" void kernel_launch(void* const* d_in, const int* in_sizes, int n_in,
                              void* d_out, int out_size, void* d_ws, size_t ws_size,
                              hipStream_t stream)
{
    const float* x      = (const float*)d_in[0];
    // d_in[1]=H, d_in[2]=W : compile-time constants (112).
    const float* g1     = (const float*)d_in[3];
    const float* b1     = (const float*)d_in[4];
    const float* w_qkv  = (const float*)d_in[5];
    const float* b_qkv  = (const float*)d_in[6];
    const float* w_proj = (const float*)d_in[7];
    const float* b_proj = (const float*)d_in[8];
    const float* g2     = (const float*)d_in[9];
    const float* b2     = (const float*)d_in[10];
    const float* w_fc1  = (const float*)d_in[11];
    const float* b_fc1  = (const float*)d_in[12];
    const float* w_fc2  = (const float*)d_in[13];
    const float* b_fc2  = (const float*)d_in[14];
    float* out = (float*)d_out;                      // f32 output

    // ws: converted bf16 weights only — 786432 elems = 1.5 MiB
    unsigned short* cWqkv  = (unsigned short*)d_ws;  // 196608
    unsigned short* cWproj = cWqkv  + 196608;        // 65536
    unsigned short* cWfc1  = cWproj + 65536;         // 262144
    unsigned short* cWfc2  = cWfc1  + 262144;        // 262144

    conv_k<<<192, 256, 0, stream>>>(w_qkv,  cWqkv,  49152);
    conv_k<<<64,  256, 0, stream>>>(w_proj, cWproj, 16384);
    conv_k<<<256, 256, 0, stream>>>(w_fc1,  cWfc1,  65536);
    conv_k<<<256, 256, 0, stream>>>(w_fc2,  cWfc2,  65536);

    attn_half_k<<<2048, 1024, 0, stream>>>(x, g1, b1, cWqkv, b_qkv, cWproj, b_proj, out);
    mlp_half_k<<<1568, 512, 0, stream>>>(g2, b2, cWfc1, b_fc1, cWfc2, b_fc2, out);
}